// Round 1
// 989.135 us; speedup vs baseline: 1.0076x; 1.0076x over previous
//
#include <hip/hip_runtime.h>

#define EPS 1e-5f

typedef __attribute__((ext_vector_type(4)))  __bf16 bf16x4;
typedef __attribute__((ext_vector_type(8)))  __bf16 bf16x8;
typedef __attribute__((ext_vector_type(4)))  float  f32x4;
typedef __attribute__((ext_vector_type(16))) float  f32x16;

// ---------------- conv1 via MFMA: (64,3,142,142) -> (64,32,132,132), k=11 ------------
__global__ __launch_bounds__(256) void k_conv1_mfma(const float* __restrict__ x,
                                                    const float* __restrict__ w,
                                                    const float* __restrict__ bias,
                                                    float* __restrict__ out)
{
    __shared__ __align__(16) __bf16 sbuf[142 * 132];
    const int tid  = threadIdx.x;
    const int lane = tid & 63;
    const int wv   = tid >> 6;
    const int half = lane >> 5;
    const int l31  = lane & 31;
    const int strip = blockIdx.x;
    const int n     = blockIdx.y;
    const int y0    = strip * 22;

    for (int i = tid; i < 32 * 11 * 48; i += 256) {
        const int co = i / (11 * 48), r = i - co * (11 * 48);
        const int kx = r / 48, j = r - kx * 48;
        const int ky = j >> 2, ci = j & 3;
        const float v = (ci < 3 && ky < 11) ? w[((co * 3 + ci) * 11 + ky) * 11 + kx] : 0.f;
        sbuf[i] = (__bf16)v;
    }
    __syncthreads();

    bf16x8 af[33];
    #pragma unroll
    for (int kx = 0; kx < 11; ++kx)
        #pragma unroll
        for (int c = 0; c < 3; ++c)
            af[kx * 3 + c] = *(const bf16x8*)&sbuf[(l31 * 11 + kx) * 48 + c * 16 + half * 8];
    float bias_v[16];
    #pragma unroll
    for (int r = 0; r < 16; ++r)
        bias_v[r] = bias[(r & 3) + 8 * (r >> 2) + 4 * half];
    __syncthreads();

    const float* xn = x + (long)n * 3 * 142 * 142;
    for (int i = tid; i < 18744; i += 256) {
        const int q = i / 142, xp = i - q * 142;
        const int yp = q >> 2, ci = q & 3;
        const int row = y0 + yp;
        const float v = (ci < 3 && row < 142) ? xn[((long)ci * 142 + row) * 142 + xp] : 0.f;
        sbuf[xp * 132 + yp * 4 + ci] = (__bf16)v;
    }
    __syncthreads();

    for (int u = wv; u < 110; u += 4) {
        const int yl = u / 5, xt = u - yl * 5;
        const int x0 = (xt < 4) ? xt * 32 : 100;
        const int px = x0 + l31;
        f32x16 acc = {};
        #pragma unroll
        for (int kx = 0; kx < 11; ++kx) {
            const int xb = (px + kx) * 132;
            #pragma unroll
            for (int c = 0; c < 3; ++c) {
                const int off = xb + (yl + c * 4 + half * 2) * 4;
                const bf16x4 lo = *(const bf16x4*)&sbuf[off];
                const bf16x4 hi = *(const bf16x4*)&sbuf[off + 4];
                const bf16x8 bf = __builtin_shufflevector(lo, hi, 0, 1, 2, 3, 4, 5, 6, 7);
                acc = __builtin_amdgcn_mfma_f32_32x32x16_bf16(af[kx * 3 + c], bf, acc, 0, 0, 0);
            }
        }
        #pragma unroll
        for (int r = 0; r < 16; ++r) {
            const int co = (r & 3) + 8 * (r >> 2) + 4 * half;
            out[(((long)n * 32 + co) * 132 + y0 + yl) * 132 + px] = acc[r] + bias_v[r];
        }
    }
}

// ---------------- region layer via MFMA + fused relu/maxpool2x2/bn2 ------------------
// Pixel->lane mapping puts each 2x2 pool window on one lane quad, so pooling is two
// shfl_xor max's. Output written directly as pooled bf16 (66x66) -> pool_bn kernel gone.
// Weight LDS layout w2[tap][ci_grp][co][8ci] -> afrag ds_read_b128 lane stride = 16B
// (conflict-free; old layout was a 16-way conflict).
template <int TH, int TW, int NIMG>
__device__ void region_pool_body(const float* __restrict__ h1,
                                 const float* __restrict__ gg, const float* __restrict__ bb,
                                 const float* __restrict__ mm, const float* __restrict__ vv,
                                 const float* __restrict__ ww, const float* __restrict__ cb,
                                 const float* __restrict__ g2, const float* __restrict__ b2,
                                 const float* __restrict__ m2, const float* __restrict__ v2,
                                 __bf16* __restrict__ hp,
                                 __bf16* act, __bf16* wlds,
                                 float* sc_s, float* sh_s, float* cb_s,
                                 float* sc2_s, float* sh2_s,
                                 int reg, int n0, int Y0, int X0)
{
    constexpr int PW   = TW + 2;
    constexpr int ROWS = TH + 2;
    constexpr int NP   = TH * TW;
    constexpr int NPT  = (NP + 31) / 32;
    constexpr int PWW  = TW / 2;          // pooled tile width
    const int tid  = threadIdx.x;
    const int lane = tid & 63;
    const int wv   = tid >> 6;
    const int half = lane >> 5;
    const int l31  = lane & 31;
    const int YP = Y0 >> 1, XP = X0 >> 1; // pooled tile origin

    if (tid < 32) {
        const float sc = gg[reg * 32 + tid] * rsqrtf(vv[reg * 32 + tid] + EPS);
        sc_s[tid] = sc;
        sh_s[tid] = bb[reg * 32 + tid] - mm[reg * 32 + tid] * sc;
        cb_s[tid] = cb[reg * 32 + tid];
        const float s2 = g2[tid] * rsqrtf(v2[tid] + EPS);
        sc2_s[tid] = s2;
        sh2_s[tid] = b2[tid] - m2[tid] * s2;
    }
    // w2[((tap*4 + (ci>>3))*32 + co)*8 + (ci&7)]  (coalesced global read side)
    for (int i = tid; i < 9216; i += 256) {
        const int co = i / 288, r = i - co * 288;
        const int ci = r / 9, tap = r - ci * 9;
        wlds[((tap * 4 + (ci >> 3)) * 32 + co) * 8 + (ci & 7)] = (__bf16)ww[(long)reg * 9216 + i];
    }
    for (int i = tid; i < ROWS * PW * 36; i += 256) act[i] = (__bf16)0.f;
    __syncthreads();

    bf16x8 afrag[18];
    #pragma unroll
    for (int c = 0; c < 18; ++c) {
        const int tap = c >> 1;
        const int grp = (c & 1) * 2 + half;
        afrag[c] = *(const bf16x8*)&wlds[((tap * 4 + grp) * 32 + l31) * 8];
    }

    for (int img = 0; img < NIMG; ++img) {
        const int n = n0 + img;
        // stage BN+ReLU activations, float2-vectorized global reads
        for (int i = tid; i < 16 * NP; i += 256) {
            const int ci = i / (NP / 2), p2 = i - ci * (NP / 2);
            const int y = p2 / PWW, x2 = p2 - y * PWW;
            const int x = 2 * x2;
            const float2 v2l = *(const float2*)&h1[(((long)n * 32 + ci) * 132 + Y0 + y) * 132 + X0 + x];
            const float a0 = fmaxf(v2l.x * sc_s[ci] + sh_s[ci], 0.f);
            const float a1 = fmaxf(v2l.y * sc_s[ci] + sh_s[ci], 0.f);
            act[((y + 1) * PW + (x + 1)) * 36 + ci] = (__bf16)a0;
            act[((y + 1) * PW + (x + 2)) * 36 + ci] = (__bf16)a1;
        }
        __syncthreads();
        for (int pt = wv; pt < NPT; pt += 4) {
            const int p = pt * 32 + l31;
            const bool valid = p < NP;
            const int pc = valid ? p : 0;
            const int sub = pc & 3;
            const int q  = pc >> 2;
            const int py = q / PWW, px = q - py * PWW;
            const int y = 2 * py + (sub >> 1);
            const int x = 2 * px + (sub & 1);
            f32x16 acc = {};
            #pragma unroll
            for (int c = 0; c < 18; ++c) {
                const int tap = c >> 1;
                const int ky = tap / 3, kx = tap - ky * 3;
                const int off = ((y + ky) * PW + (x + kx)) * 36 + (c & 1) * 16 + half * 8;
                const bf16x4 lo = *(const bf16x4*)&act[off];
                const bf16x4 hi = *(const bf16x4*)&act[off + 4];
                const bf16x8 bfr = __builtin_shufflevector(lo, hi, 0, 1, 2, 3, 4, 5, 6, 7);
                acc = __builtin_amdgcn_mfma_f32_32x32x16_bf16(afrag[c], bfr, acc, 0, 0, 0);
            }
            // residual + relu + 2x2 maxpool (quad shuffle) + bn2, pooled bf16 store
            #pragma unroll
            for (int r = 0; r < 16; ++r) {
                const int co = (r & 3) + 8 * (r >> 2) + 4 * half;
                const long o = (((long)n * 32 + co) * 132 + Y0 + y) * 132 + X0 + x;
                float v = acc[r] + cb_s[co] + h1[o];
                v = fmaxf(v, 0.f);
                v = fmaxf(v, __shfl_xor(v, 1));
                v = fmaxf(v, __shfl_xor(v, 2));
                if (valid && sub == 0) {
                    const float w = v * sc2_s[co] + sh2_s[co];
                    hp[(((long)n * 32 + co) * 66 + YP + py) * 66 + XP + px] = (__bf16)w;
                }
            }
        }
        __syncthreads();
    }
}

__global__ __launch_bounds__(256) void k_region_pool(const float* __restrict__ h1,
                                                     const float* __restrict__ gg,
                                                     const float* __restrict__ bb,
                                                     const float* __restrict__ mm,
                                                     const float* __restrict__ vv,
                                                     const float* __restrict__ ww,
                                                     const float* __restrict__ cb,
                                                     const float* __restrict__ g2,
                                                     const float* __restrict__ b2,
                                                     const float* __restrict__ m2,
                                                     const float* __restrict__ v2,
                                                     __bf16* __restrict__ hp)
{
    __shared__ __align__(16) __bf16 act[20 * 20 * 36];   // 28.8 KB
    __shared__ __align__(16) __bf16 wlds[9216];          // 18.4 KB
    __shared__ float sc_s[32], sh_s[32], cb_s[32], sc2_s[32], sh2_s[32];
    const int reg = blockIdx.x;
    const int ri = reg >> 3, rj = reg & 7;
    const int n0 = blockIdx.y * 8;
    const int Y0 = ri * 18, X0 = rj * 18;
    if (ri < 7 && rj < 7)
        region_pool_body<18, 18, 8>(h1, gg, bb, mm, vv, ww, cb, g2, b2, m2, v2, hp,
                                    act, wlds, sc_s, sh_s, cb_s, sc2_s, sh2_s, reg, n0, Y0, X0);
    else if (ri < 7)
        region_pool_body<18, 6, 8>(h1, gg, bb, mm, vv, ww, cb, g2, b2, m2, v2, hp,
                                   act, wlds, sc_s, sh_s, cb_s, sc2_s, sh2_s, reg, n0, Y0, X0);
    else if (rj < 7)
        region_pool_body<6, 18, 8>(h1, gg, bb, mm, vv, ww, cb, g2, b2, m2, v2, hp,
                                   act, wlds, sc_s, sh_s, cb_s, sc2_s, sh2_s, reg, n0, Y0, X0);
    else
        region_pool_body<6, 6, 8>(h1, gg, bb, mm, vv, ww, cb, g2, b2, m2, v2, hp,
                                  act, wlds, sc_s, sh_s, cb_s, sc2_s, sh2_s, reg, n0, Y0, X0);
}

// ---------------- weight prep for MFMA convs: w[co][ci][ky][kx] -> frag order --------
__global__ void k_wprep(const float* __restrict__ w, __bf16* __restrict__ wA,
                        int CIN, int KS, int NCHUNK)
{
    const int NG = CIN / 16;
    const int total = NG * NCHUNK * 512;
    const int i = blockIdx.x * 256 + threadIdx.x;
    if (i >= total) return;
    const int j   = i & 7;
    const int co  = (i >> 3) & 15;
    const int quad = (i >> 7) & 3;
    const int ch  = (i >> 9) % NCHUNK;
    const int g   = (i >> 9) / NCHUNK;
    const int k   = ch * 32 + quad * 8 + j;
    const int t   = k >> 4, c = k & 15;
    float v = 0.f;
    if (t < KS * KS) v = w[((co * CIN + g * 16 + c) * KS + t / KS) * KS + t % KS];
    wA[i] = (__bf16)v;
}

// ---------------- stride-1 conv + relu via MFMA 16x16x32, COUT=16 --------------------
// TIN/TOUT templated: bf16 in/out where the consumer is an MFMA kernel (it would
// round to bf16 in LDS staging anyway -> bit-identical, half the HBM traffic).
template <typename TIN, typename TOUT, int CIN, int KS, int HIN, int HOUT, int R>
__global__ __launch_bounds__(256) void k_conv_mfma(const TIN* __restrict__ in,
                                                   const __bf16* __restrict__ wA,
                                                   const float* __restrict__ bias,
                                                   TOUT* __restrict__ out)
{
    constexpr int NG     = CIN / 16;
    constexpr int TAPS   = KS * KS;
    constexpr int NCHUNK = (TAPS * 16 + 31) / 32;      // per ci-group
    constexpr int NROWS  = R + KS - 1;
    constexpr int NP     = R * HOUT;
    constexpr int NTIL   = (NP + 15) / 16;
    constexpr int NT     = (NTIL + 3) / 4;
    __shared__ __align__(16) __bf16 act[NROWS * HIN * 20];
    __shared__ __align__(16) __bf16 wl[NCHUNK * 512];
    const int tid  = threadIdx.x;
    const int lane = tid & 63;
    const int wv   = tid >> 6;
    const int quad = lane >> 4;
    const int m    = lane & 15;
    const int n    = blockIdx.y;
    int y0 = blockIdx.x * R; if (y0 > HOUT - R) y0 = HOUT - R;

    int yl[NT], xx[NT]; bool val[NT];
    #pragma unroll
    for (int t = 0; t < NT; ++t) {
        const int til = wv + t * 4;
        int p = til * 16 + m;
        val[t] = (til < NTIL) && (p < NP);
        if (!val[t]) p = m;
        yl[t] = p / HOUT; xx[t] = p - yl[t] * HOUT;
    }
    f32x4 acc[NT];
    #pragma unroll
    for (int t = 0; t < NT; ++t) acc[t] = (f32x4){0.f, 0.f, 0.f, 0.f};

    for (int g = 0; g < NG; ++g) {
        if (g) __syncthreads();
        for (int i = tid; i < NCHUNK * 256; i += 256)
            ((unsigned*)wl)[i] = ((const unsigned*)wA)[g * NCHUNK * 256 + i];
        for (int i = tid; i < 16 * NROWS * HIN; i += 256) {
            const int c = i / (NROWS * HIN), px = i - c * (NROWS * HIN);
            const int r = px / HIN, xc = px - r * HIN;
            act[px * 20 + c] = (__bf16)in[(((long)n * CIN + g * 16 + c) * HIN + y0 + r) * HIN + xc];
        }
        __syncthreads();
        for (int ch = 0; ch < NCHUNK; ++ch) {
            const bf16x8 a = *(const bf16x8*)&wl[(ch * 4 + quad) * 128 + m * 8];
            const int kbase = ch * 32 + quad * 8;
            int t = kbase >> 4;
            const int c0 = kbase & 15;                 // 0 or 8
            int ky = 0, kx = 0;
            if (t < TAPS) { ky = t / KS; kx = t - ky * KS; }
            #pragma unroll
            for (int tt = 0; tt < NT; ++tt) {
                const int off = ((yl[tt] + ky) * HIN + xx[tt] + kx) * 20 + c0;
                const bf16x4 lo = *(const bf16x4*)&act[off];
                const bf16x4 hi = *(const bf16x4*)&act[off + 4];
                const bf16x8 b = __builtin_shufflevector(lo, hi, 0, 1, 2, 3, 4, 5, 6, 7);
                acc[tt] = __builtin_amdgcn_mfma_f32_16x16x32_bf16(a, b, acc[tt], 0, 0, 0);
            }
        }
    }
    #pragma unroll
    for (int tt = 0; tt < NT; ++tt) {
        if (!val[tt]) continue;
        #pragma unroll
        for (int r = 0; r < 4; ++r) {
            const int co = quad * 4 + r;
            out[(((long)n * 16 + co) * HOUT + y0 + yl[tt]) * HOUT + xx[tt]]
                = (TOUT)fmaxf(acc[tt][r] + bias[co], 0.f);
        }
    }
}

// ---------------- strided conv (conv4 only); bf16 out (conv5 rounds anyway) ----------
template <int CIN, int KS, int STRIDE, int HIN, int HOUT>
__global__ __launch_bounds__(256) void k_conv(const float* __restrict__ in,
                                              const float* __restrict__ w,
                                              const float* __restrict__ bias,
                                              __bf16* __restrict__ out)
{
    const int co = blockIdx.y, n = blockIdx.z;
    constexpr int GR  = (HOUT + 3) / 4;
    constexpr int WSZ = CIN * KS * KS;
    constexpr int LEN = KS + 3 * STRIDE;
    __shared__ float ws[WSZ];
    for (int i = threadIdx.x; i < WSZ; i += 256) ws[i] = w[co * WSZ + i];
    __syncthreads();
    const int g = blockIdx.x * 256 + threadIdx.x;
    if (g >= HOUT * GR) return;
    const int y = g / GR;
    int x0 = (g - y * GR) * 4;
    if (x0 > HOUT - 4) x0 = HOUT - 4;
    float a0 = bias[co], a1 = a0, a2 = a0, a3 = a0;
    const float* base = in + (long)n * CIN * HIN * HIN;
    for (int ci = 0; ci < CIN; ++ci) {
        for (int ky = 0; ky < KS; ++ky) {
            const float* row = base + ((long)ci * HIN + y * STRIDE + ky) * HIN + x0 * STRIDE;
            float r[LEN];
            #pragma unroll
            for (int i = 0; i < LEN; ++i) r[i] = row[i];
            const float* wr = ws + (ci * KS + ky) * KS;
            #pragma unroll
            for (int kx = 0; kx < KS; ++kx) {
                const float wv = wr[kx];
                a0 = fmaf(wv, r[kx],              a0);
                a1 = fmaf(wv, r[kx + STRIDE],     a1);
                a2 = fmaf(wv, r[kx + 2 * STRIDE], a2);
                a3 = fmaf(wv, r[kx + 3 * STRIDE], a3);
            }
        }
    }
    __bf16* o = out + (((long)n * 16 + co) * HOUT + y) * HOUT + x0;
    o[0] = (__bf16)fmaxf(a0, 0.f); o[1] = (__bf16)fmaxf(a1, 0.f);
    o[2] = (__bf16)fmaxf(a2, 0.f); o[3] = (__bf16)fmaxf(a3, 0.f);
}

// ---------------- fc GEMM: C[64][N] += A[64][K] * W[N][K]^T, LDS-tiled, split-K ------
__global__ __launch_bounds__(256) void k_fc2(const float* __restrict__ A,
                                             const float* __restrict__ W,
                                             float* __restrict__ C,
                                             int N, int K, int kchunk)
{
    __shared__ float As[64][68];
    __shared__ float Bs[64][132];
    const int n0 = blockIdx.x * 128;
    const int kbeg = blockIdx.y * kchunk;
    const int tid = threadIdx.x;
    const int tm = tid >> 4, tn = tid & 15;
    const int am = tid >> 2, ac = tid & 3;
    const int bn = tid >> 1, bh = tid & 1;
    float acc[4][8] = {};
    for (int k0 = kbeg; k0 < kbeg + kchunk; k0 += 64) {
        #pragma unroll
        for (int q = 0; q < 4; ++q) {
            const int kk = ac * 16 + q * 4;
            const float4 v = *(const float4*)&A[(long)am * K + k0 + kk];
            As[kk + 0][am] = v.x; As[kk + 1][am] = v.y;
            As[kk + 2][am] = v.z; As[kk + 3][am] = v.w;
        }
        const int nn = n0 + bn;
        if (nn < N) {
            #pragma unroll
            for (int q = 0; q < 8; ++q) {
                const int kk = bh * 32 + q * 4;
                const float4 v = *(const float4*)&W[(long)nn * K + k0 + kk];
                Bs[kk + 0][bn] = v.x; Bs[kk + 1][bn] = v.y;
                Bs[kk + 2][bn] = v.z; Bs[kk + 3][bn] = v.w;
            }
        }
        __syncthreads();
        #pragma unroll 4
        for (int kk = 0; kk < 64; ++kk) {
            float a[4], b[8];
            #pragma unroll
            for (int i = 0; i < 4; ++i) a[i] = As[kk][tm * 4 + i];
            #pragma unroll
            for (int j = 0; j < 8; ++j) b[j] = Bs[kk][tn * 8 + j];
            #pragma unroll
            for (int i = 0; i < 4; ++i)
                #pragma unroll
                for (int j = 0; j < 8; ++j)
                    acc[i][j] = fmaf(a[i], b[j], acc[i][j]);
        }
        __syncthreads();
    }
    #pragma unroll
    for (int i = 0; i < 4; ++i) {
        const int m = tm * 4 + i;
        #pragma unroll
        for (int j = 0; j < 8; ++j) {
            const int nn = n0 + tn * 8 + j;
            if (nn < N) atomicAdd(&C[(long)m * N + nn], acc[i][j]);
        }
    }
}

__global__ __launch_bounds__(256) void k_bias_act(const float* __restrict__ C,
                                                  const float* __restrict__ bias,
                                                  float* __restrict__ out,
                                                  int N, int total, int relu)
{
    const int i = blockIdx.x * 256 + threadIdx.x;
    if (i >= total) return;
    float v = C[i] + bias[i % N];
    if (relu) v = fmaxf(v, 0.f);
    out[i] = v;
}

extern "C" void kernel_launch(void* const* d_in, const int* in_sizes, int n_in,
                              void* d_out, int out_size, void* d_ws, size_t ws_size,
                              hipStream_t stream)
{
    (void)in_sizes; (void)n_in; (void)out_size; (void)ws_size;
    const float* x       = (const float*)d_in[0];
    const float* conv1_w = (const float*)d_in[1];
    const float* conv1_b = (const float*)d_in[2];
    const float* rg_g    = (const float*)d_in[3];
    const float* rg_b    = (const float*)d_in[4];
    const float* rg_m    = (const float*)d_in[5];
    const float* rg_v    = (const float*)d_in[6];
    const float* rg_w    = (const float*)d_in[7];
    const float* rg_cb   = (const float*)d_in[8];
    const float* bn2_g   = (const float*)d_in[9];
    const float* bn2_b   = (const float*)d_in[10];
    const float* bn2_m   = (const float*)d_in[11];
    const float* bn2_v   = (const float*)d_in[12];
    const float* conv2_w = (const float*)d_in[13];
    const float* conv2_b = (const float*)d_in[14];
    const float* conv3_w = (const float*)d_in[15];
    const float* conv3_b = (const float*)d_in[16];
    const float* conv4_w = (const float*)d_in[17];
    const float* conv4_b = (const float*)d_in[18];
    const float* conv5_w = (const float*)d_in[19];
    const float* conv5_b = (const float*)d_in[20];
    const float* fc1_w   = (const float*)d_in[21];
    const float* fc1_b   = (const float*)d_in[22];
    const float* fc2_w   = (const float*)d_in[23];
    const float* fc2_b   = (const float*)d_in[24];
    const float* fc3_w   = (const float*)d_in[25];
    const float* fc3_b   = (const float*)d_in[26];

    float* ws = (float*)d_ws;
    float*  h1  = ws;                                // conv1 out f32 (64,32,132,132): 35,684,352 f
    __bf16* hp  = (__bf16*)(ws + 35684352);          // pooled bn2 out bf16 (64,32,66,66): 4,460,544 f
    __bf16* wA2 = (__bf16*)(ws + 40144896);          // 32768 bf16
    __bf16* wA3 = (__bf16*)(ws + 40161280);          // 16384 bf16
    __bf16* wA5 = (__bf16*)(ws + 40169472);          //  6656 bf16
    __bf16* h3  = (__bf16*)(ws + 40173568);          // conv2 out bf16 (64,16,59,59): 1,782,272 f
    float*  h4  = ws + 41955840;                     // conv3 out f32 (64,16,52,52): 2,768,896 f
    __bf16* h5  = (__bf16*)(ws + 44724736);          // conv4 out bf16 (64,16,24,24): 294,912 f
    float*  h6  = ws + 45019648;                     // conv5 out f32 == fc1 input (64,6400)
    float*  f1  = ws + 45429248;                     // fc1 out (64,4096)
    float*  f2  = ws + 45691392;                     // fc2 out (64,2048)
    float*  f3  = ws + 45822464;                     // fc3 tmp (64,12)

    k_conv1_mfma<<<dim3(6, 64), 256, 0, stream>>>(x, conv1_w, conv1_b, h1);
    k_region_pool<<<dim3(64, 8), 256, 0, stream>>>(h1, rg_g, rg_b, rg_m, rg_v, rg_w, rg_cb,
                                                   bn2_g, bn2_b, bn2_m, bn2_v, hp);

    k_wprep<<<dim3(128), 256, 0, stream>>>(conv2_w, wA2, 32, 8, 32);
    k_wprep<<<dim3(64), 256, 0, stream>>>(conv3_w, wA3, 16, 8, 32);
    k_wprep<<<dim3(26), 256, 0, stream>>>(conv5_w, wA5, 16, 5, 13);

    k_conv_mfma<__bf16, __bf16, 32, 8, 66, 59, 4><<<dim3(15, 64), 256, 0, stream>>>(hp, wA2, conv2_b, h3);
    k_conv_mfma<__bf16, float, 16, 8, 59, 52, 4><<<dim3(13, 64), 256, 0, stream>>>(h3, wA3, conv3_b, h4);
    k_conv<16, 6, 2, 52, 24><<<dim3(1, 16, 64), 256, 0, stream>>>(h4, conv4_w, conv4_b, h5);
    k_conv_mfma<__bf16, float, 16, 5, 24, 20, 10><<<dim3(2, 64), 256, 0, stream>>>(h5, wA5, conv5_b, h6);

    hipMemsetAsync(f1, 0, 262144 * sizeof(float), stream);
    k_fc2<<<dim3(32, 10), 256, 0, stream>>>(h6, fc1_w, f1, 4096, 6400, 640);
    k_bias_act<<<dim3((262144 + 255) / 256), 256, 0, stream>>>(f1, fc1_b, f1, 4096, 262144, 1);

    hipMemsetAsync(f2, 0, 131072 * sizeof(float), stream);
    k_fc2<<<dim3(16, 16), 256, 0, stream>>>(f1, fc2_w, f2, 2048, 4096, 256);
    k_bias_act<<<dim3((131072 + 255) / 256), 256, 0, stream>>>(f2, fc2_b, f2, 2048, 131072, 1);

    hipMemsetAsync(f3, 0, 768 * sizeof(float), stream);
    k_fc2<<<dim3(1, 16), 256, 0, stream>>>(f2, fc3_w, f3, 12, 2048, 128);
    k_bias_act<<<dim3(3), 256, 0, stream>>>(f3, fc3_b, (float*)d_out, 12, 768, 0);
}

// Round 3
// 751.856 us; speedup vs baseline: 1.3256x; 1.3156x over previous
//
#include <hip/hip_runtime.h>

#define EPS 1e-5f

typedef __attribute__((ext_vector_type(4)))  __bf16 bf16x4;
typedef __attribute__((ext_vector_type(8)))  __bf16 bf16x8;
typedef __attribute__((ext_vector_type(4)))  float  f32x4;
typedef __attribute__((ext_vector_type(16))) float  f32x16;

// ============ fused conv1 + region(BN+ReLU+3x3conv+residual) + ReLU+maxpool+BN2 ======
// One block per (region, 8-image group). Region tiles partition the 132x132 plane and
// the region conv needs NO halo (per-tile zero padding), so conv1 is computed per tile
// from a small x slab; the conv1 accumulator IS the residual (pre-loaded into the
// region-conv accumulator), and h1 never exists in HBM.
template <int TH, int TW, int NIMG>
__device__ void fused_body(const float* __restrict__ xg,
                           const float* __restrict__ c1w, const float* __restrict__ c1b,
                           const float* __restrict__ gg, const float* __restrict__ bb,
                           const float* __restrict__ mm, const float* __restrict__ vv,
                           const float* __restrict__ ww, const float* __restrict__ cbp,
                           const float* __restrict__ g2, const float* __restrict__ b2,
                           const float* __restrict__ m2, const float* __restrict__ v2,
                           __bf16* __restrict__ hp,
                           __bf16* act, __bf16* wlds1, __bf16* sx, __bf16* zbuf,
                           float* prm,
                           int reg, int n0, int Y0, int X0)
{
    constexpr int C     = TW + 10;        // x-slab cols
    constexpr int RR    = TH + 10;        // x-slab real rows
    constexpr int SSTR  = 4 * (TH + 11);  // x-slab col stride (elems, incl. pad row)
    constexpr int NP    = TH * TW;
    constexpr int NPT   = (NP + 31) / 32;
    constexpr int NT    = (NPT + 3) / 4;
    constexpr int PWW   = TW / 2;         // pooled tile width
    constexpr int TOT   = 3 * RR * C;
    constexpr int NLOAD = (TOT + 255) / 256;

    const int tid  = threadIdx.x;
    const int lane = tid & 63;
    const int wv   = tid >> 6;
    const int half = lane >> 5;
    const int l31  = lane & 31;
    const int YP = Y0 >> 1, XP = X0 >> 1;

    // ---- one-time prep --------------------------------------------------------------
    if (tid < 32) {
        const float sc = gg[reg * 32 + tid] * rsqrtf(vv[reg * 32 + tid] + EPS);
        const float b1 = c1b[tid];
        prm[tid]       = sc;                                          // bn1 scale
        prm[32 + tid]  = bb[reg * 32 + tid] - mm[reg * 32 + tid] * sc + sc * b1; // bn1 shift (conv1 bias folded)
        prm[64 + tid]  = cbp[reg * 32 + tid] + b1;                    // region bias + conv1 bias (residual path)
        const float s2 = g2[tid] * rsqrtf(v2[tid] + EPS);
        prm[96 + tid]  = s2;                                          // bn2 scale
        prm[128 + tid] = b2[tid] - m2[tid] * s2;                      // bn2 shift
    }
    // conv1 weights: wlds1[(((kx*3+c)*2+half)*32+co)*8+j], k48 = c*16+half*8+j -> (ky=k48>>2, ci=k48&3)
    for (int i = tid; i < 16896; i += 256) {
        const int j = i & 7, co = (i >> 3) & 31, hf = (i >> 8) & 1, cc = i >> 9;
        const int c = cc % 3, kx = cc / 3;
        const int k48 = c * 16 + hf * 8 + j, ky = k48 >> 2, ci = k48 & 3;
        const float v = (ci < 3 && ky < 11) ? c1w[((co * 3 + ci) * 11 + ky) * 11 + kx] : 0.f;
        wlds1[i] = (__bf16)v;
    }
    // region weights bounced through act space: w2[((tap*4+(ci>>3))*32+co)*8+(ci&7)]
    for (int i = tid; i < 9216; i += 256) {
        const int co = i / 288, r = i - co * 288;
        const int ci = r / 9, tap = r - ci * 9;
        act[((tap * 4 + (ci >> 3)) * 32 + co) * 8 + (ci & 7)] = (__bf16)ww[(long)reg * 9216 + i];
    }
    // zero x slab once: ci=3 slots and pad row stay zero forever (MFMA K padding)
    for (int i = tid; i < C * SSTR; i += 256) sx[i] = (__bf16)0.f;
    __syncthreads();

    bf16x8 afrag[18];
    #pragma unroll
    for (int c = 0; c < 18; ++c) {
        const int tap = c >> 1;
        const int grp = (c & 1) * 2 + half;
        afrag[c] = *(const bf16x8*)&act[((tap * 4 + grp) * 32 + l31) * 8];
    }

    // per-wave pixel tiles, quad-pool mapping (each lane quad = one 2x2 pool window)
    const int sub = l31 & 3;
    int py[NT], px[NT], yy0[NT], xx0[NT]; bool val[NT];
    #pragma unroll
    for (int t = 0; t < NT; ++t) {
        const int til = wv + t * 4;
        int p = til * 32 + l31;
        val[t] = (til < NPT) && (p < NP);
        if (!val[t]) p = l31;
        const int q = p >> 2;
        py[t] = q / PWW; px[t] = q - py[t] * PWW;
        yy0[t] = 2 * py[t] + ((p & 3) >> 1);
        xx0[t] = 2 * px[t] + (p & 1);
    }

    // prefetch img0 x-slab into registers
    float pf[NLOAD];
    #pragma unroll
    for (int k = 0; k < NLOAD; ++k) {
        const int idx = tid + k * 256;
        float v = 0.f;
        if (idx < TOT) {
            const int col = idx % C, rr = idx / C;
            const int row = rr % RR, ci = rr / RR;
            v = xg[(((long)n0 * 3 + ci) * 142 + Y0 + row) * 142 + X0 + col];
        }
        pf[k] = v;
    }
    __syncthreads();   // afrag reads complete before act is overwritten in img loop

    for (int img = 0; img < NIMG; ++img) {
        const int n = n0 + img;
        // write prefetched x -> LDS slab (bf16)
        #pragma unroll
        for (int k = 0; k < NLOAD; ++k) {
            const int idx = tid + k * 256;
            if (idx < TOT) {
                const int col = idx % C, rr = idx / C;
                const int row = rr % RR, ci = rr / RR;
                sx[col * SSTR + row * 4 + ci] = (__bf16)pf[k];
            }
        }
        __syncthreads();
        // issue next img's global loads now; latency hides under conv1+region compute
        if (img + 1 < NIMG) {
            #pragma unroll
            for (int k = 0; k < NLOAD; ++k) {
                const int idx = tid + k * 256;
                if (idx < TOT) {
                    const int col = idx % C, rr = idx / C;
                    const int row = rr % RR, ci = rr / RR;
                    pf[k] = xg[(((long)(n + 1) * 3 + ci) * 142 + Y0 + row) * 142 + X0 + col];
                }
            }
        }
        // ---- conv1: a1 = conv1(x) (no bias), same (kx,c) accumulation order
        f32x16 a1[NT];
        #pragma unroll
        for (int t = 0; t < NT; ++t) a1[t] = (f32x16){};
        for (int kx = 0; kx < 11; ++kx) {
            #pragma unroll
            for (int c = 0; c < 3; ++c) {
                const bf16x8 A = *(const bf16x8*)&wlds1[(((kx * 3 + c) * 2 + half) * 32 + l31) * 8];
                #pragma unroll
                for (int t = 0; t < NT; ++t) {
                    if (wv + t * 4 < NPT) {
                        const int off = (xx0[t] + kx) * SSTR + (yy0[t] + c * 4 + half * 2) * 4;
                        const bf16x4 lo = *(const bf16x4*)&sx[off];
                        const bf16x4 hi = *(const bf16x4*)&sx[off + 4];
                        a1[t] = __builtin_amdgcn_mfma_f32_32x32x16_bf16(
                                    A, __builtin_shufflevector(lo, hi, 0, 1, 2, 3, 4, 5, 6, 7),
                                    a1[t], 0, 0, 0);
                    }
                }
            }
        }
        // ---- act = bf16(relu(bn1(acc1 + bias))), packed 4-co b64 writes
        #pragma unroll
        for (int t = 0; t < NT; ++t) {
            if (val[t]) {
                const int pix = yy0[t] * TW + xx0[t];
                #pragma unroll
                for (int g = 0; g < 4; ++g) {
                    bf16x4 pk;
                    #pragma unroll
                    for (int j = 0; j < 4; ++j) {
                        const int co = 4 * half + 8 * g + j;
                        pk[j] = (__bf16)fmaxf(a1[t][4 * g + j] * prm[co] + prm[32 + co], 0.f);
                    }
                    *(bf16x4*)&act[pix * 36 + 8 * g + 4 * half] = pk;
                }
            }
        }
        __syncthreads();
        // ---- region 3x3 conv; accumulator starts as a1 (residual pre-added, frees a1)
        f32x16 ar[NT];
        #pragma unroll
        for (int t = 0; t < NT; ++t) ar[t] = a1[t];
        #pragma unroll
        for (int c = 0; c < 18; ++c) {
            const int tap = c >> 1;
            const int ky = tap / 3, kxx = tap - ky * 3;
            #pragma unroll
            for (int t = 0; t < NT; ++t) {
                if (wv + t * 4 < NPT) {
                    const int yy = yy0[t] + ky - 1, xx = xx0[t] + kxx - 1;
                    const bool in = ((unsigned)yy < (unsigned)TH) && ((unsigned)xx < (unsigned)TW);
                    const __bf16* src = in ? &act[(yy * TW + xx) * 36 + (c & 1) * 16 + half * 8] : zbuf;
                    const bf16x4 lo = *(const bf16x4*)src;
                    const bf16x4 hi = *(const bf16x4*)(src + 4);
                    ar[t] = __builtin_amdgcn_mfma_f32_32x32x16_bf16(
                                afrag[c], __builtin_shufflevector(lo, hi, 0, 1, 2, 3, 4, 5, 6, 7),
                                ar[t], 0, 0, 0);
                }
            }
        }
        // ---- epilogue: + region bias, relu, 2x2 quad-pool, bn2, store
        #pragma unroll
        for (int t = 0; t < NT; ++t) {
            if (wv + t * 4 < NPT) {
                #pragma unroll
                for (int r = 0; r < 16; ++r) {
                    const int co = (r & 3) + 8 * (r >> 2) + 4 * half;
                    float v = ar[t][r] + prm[64 + co];
                    v = fmaxf(v, 0.f);
                    v = fmaxf(v, __shfl_xor(v, 1));
                    v = fmaxf(v, __shfl_xor(v, 2));
                    if (val[t] && sub == 0) {
                        hp[(((long)n * 32 + co) * 66 + YP + py[t]) * 66 + XP + px[t]]
                            = (__bf16)(v * prm[96 + co] + prm[128 + co]);
                    }
                }
            }
        }
        // loop-top sx write is safe: conv1 reads of sx all precede the mid barrier,
        // and act writes of img+1 happen only after the next top barrier.
    }
}

__global__ __launch_bounds__(256, 2) void k_fused(const float* __restrict__ xg,
                                                  const float* __restrict__ c1w,
                                                  const float* __restrict__ c1b,
                                                  const float* __restrict__ gg,
                                                  const float* __restrict__ bb,
                                                  const float* __restrict__ mm,
                                                  const float* __restrict__ vv,
                                                  const float* __restrict__ ww,
                                                  const float* __restrict__ cbp,
                                                  const float* __restrict__ g2,
                                                  const float* __restrict__ b2,
                                                  const float* __restrict__ m2,
                                                  const float* __restrict__ v2,
                                                  __bf16* __restrict__ hp)
{
    __shared__ __align__(16) __bf16 act[11664];     // 18*18*36 (also w2 bounce space)
    __shared__ __align__(16) __bf16 wlds1[16896];   // conv1 weights, frag order
    __shared__ __align__(16) __bf16 sx[3248];       // x slab, 28 cols * 116
    __shared__ __align__(16) __bf16 zbuf[8];        // zero B-frag source
    __shared__ float prm[160];
    if (threadIdx.x < 8) zbuf[threadIdx.x] = (__bf16)0.f;
    const int reg = blockIdx.x;
    const int ri = reg >> 3, rj = reg & 7;
    const int n0 = blockIdx.y * 8;
    const int Y0 = ri * 18, X0 = rj * 18;
    if (ri < 7 && rj < 7)
        fused_body<18, 18, 8>(xg, c1w, c1b, gg, bb, mm, vv, ww, cbp, g2, b2, m2, v2, hp,
                              act, wlds1, sx, zbuf, prm, reg, n0, Y0, X0);
    else if (ri < 7)
        fused_body<18, 6, 8>(xg, c1w, c1b, gg, bb, mm, vv, ww, cbp, g2, b2, m2, v2, hp,
                             act, wlds1, sx, zbuf, prm, reg, n0, Y0, X0);
    else if (rj < 7)
        fused_body<6, 18, 8>(xg, c1w, c1b, gg, bb, mm, vv, ww, cbp, g2, b2, m2, v2, hp,
                             act, wlds1, sx, zbuf, prm, reg, n0, Y0, X0);
    else
        fused_body<6, 6, 8>(xg, c1w, c1b, gg, bb, mm, vv, ww, cbp, g2, b2, m2, v2, hp,
                            act, wlds1, sx, zbuf, prm, reg, n0, Y0, X0);
}

// ---------------- weight prep for MFMA convs: w[co][ci][ky][kx] -> frag order --------
__global__ void k_wprep(const float* __restrict__ w, __bf16* __restrict__ wA,
                        int CIN, int KS, int NCHUNK)
{
    const int NG = CIN / 16;
    const int total = NG * NCHUNK * 512;
    const int i = blockIdx.x * 256 + threadIdx.x;
    if (i >= total) return;
    const int j   = i & 7;
    const int co  = (i >> 3) & 15;
    const int quad = (i >> 7) & 3;
    const int ch  = (i >> 9) % NCHUNK;
    const int g   = (i >> 9) / NCHUNK;
    const int k   = ch * 32 + quad * 8 + j;
    const int t   = k >> 4, c = k & 15;
    float v = 0.f;
    if (t < KS * KS) v = w[((co * CIN + g * 16 + c) * KS + t / KS) * KS + t % KS];
    wA[i] = (__bf16)v;
}

// ---------------- stride-1 conv + relu via MFMA 16x16x32, COUT=16 --------------------
template <typename TIN, typename TOUT, int CIN, int KS, int HIN, int HOUT, int R>
__global__ __launch_bounds__(256) void k_conv_mfma(const TIN* __restrict__ in,
                                                   const __bf16* __restrict__ wA,
                                                   const float* __restrict__ bias,
                                                   TOUT* __restrict__ out)
{
    constexpr int NG     = CIN / 16;
    constexpr int TAPS   = KS * KS;
    constexpr int NCHUNK = (TAPS * 16 + 31) / 32;      // per ci-group
    constexpr int NROWS  = R + KS - 1;
    constexpr int NP     = R * HOUT;
    constexpr int NTIL   = (NP + 15) / 16;
    constexpr int NT     = (NTIL + 3) / 4;
    __shared__ __align__(16) __bf16 act[NROWS * HIN * 20];
    __shared__ __align__(16) __bf16 wl[NCHUNK * 512];
    const int tid  = threadIdx.x;
    const int lane = tid & 63;
    const int wv   = tid >> 6;
    const int quad = lane >> 4;
    const int m    = lane & 15;
    const int n    = blockIdx.y;
    int y0 = blockIdx.x * R; if (y0 > HOUT - R) y0 = HOUT - R;

    int yl[NT], xx[NT]; bool val[NT];
    #pragma unroll
    for (int t = 0; t < NT; ++t) {
        const int til = wv + t * 4;
        int p = til * 16 + m;
        val[t] = (til < NTIL) && (p < NP);
        if (!val[t]) p = m;
        yl[t] = p / HOUT; xx[t] = p - yl[t] * HOUT;
    }
    f32x4 acc[NT];
    #pragma unroll
    for (int t = 0; t < NT; ++t) acc[t] = (f32x4){0.f, 0.f, 0.f, 0.f};

    for (int g = 0; g < NG; ++g) {
        if (g) __syncthreads();
        for (int i = tid; i < NCHUNK * 256; i += 256)
            ((unsigned*)wl)[i] = ((const unsigned*)wA)[g * NCHUNK * 256 + i];
        for (int i = tid; i < 16 * NROWS * HIN; i += 256) {
            const int c = i / (NROWS * HIN), px = i - c * (NROWS * HIN);
            const int r = px / HIN, xc = px - r * HIN;
            act[px * 20 + c] = (__bf16)in[(((long)n * CIN + g * 16 + c) * HIN + y0 + r) * HIN + xc];
        }
        __syncthreads();
        for (int ch = 0; ch < NCHUNK; ++ch) {
            const bf16x8 a = *(const bf16x8*)&wl[(ch * 4 + quad) * 128 + m * 8];
            const int kbase = ch * 32 + quad * 8;
            int t = kbase >> 4;
            const int c0 = kbase & 15;                 // 0 or 8
            int ky = 0, kx = 0;
            if (t < TAPS) { ky = t / KS; kx = t - ky * KS; }
            #pragma unroll
            for (int tt = 0; tt < NT; ++tt) {
                const int off = ((yl[tt] + ky) * HIN + xx[tt] + kx) * 20 + c0;
                const bf16x4 lo = *(const bf16x4*)&act[off];
                const bf16x4 hi = *(const bf16x4*)&act[off + 4];
                const bf16x8 b = __builtin_shufflevector(lo, hi, 0, 1, 2, 3, 4, 5, 6, 7);
                acc[tt] = __builtin_amdgcn_mfma_f32_16x16x32_bf16(a, b, acc[tt], 0, 0, 0);
            }
        }
    }
    #pragma unroll
    for (int tt = 0; tt < NT; ++tt) {
        if (!val[tt]) continue;
        #pragma unroll
        for (int r = 0; r < 4; ++r) {
            const int co = quad * 4 + r;
            out[(((long)n * 16 + co) * HOUT + y0 + yl[tt]) * HOUT + xx[tt]]
                = (TOUT)fmaxf(acc[tt][r] + bias[co], 0.f);
        }
    }
}

// ---------------- strided conv (conv4 only); bf16 out (conv5 rounds anyway) ----------
template <int CIN, int KS, int STRIDE, int HIN, int HOUT>
__global__ __launch_bounds__(256) void k_conv(const float* __restrict__ in,
                                              const float* __restrict__ w,
                                              const float* __restrict__ bias,
                                              __bf16* __restrict__ out)
{
    const int co = blockIdx.y, n = blockIdx.z;
    constexpr int GR  = (HOUT + 3) / 4;
    constexpr int WSZ = CIN * KS * KS;
    constexpr int LEN = KS + 3 * STRIDE;
    __shared__ float ws[WSZ];
    for (int i = threadIdx.x; i < WSZ; i += 256) ws[i] = w[co * WSZ + i];
    __syncthreads();
    const int g = blockIdx.x * 256 + threadIdx.x;
    if (g >= HOUT * GR) return;
    const int y = g / GR;
    int x0 = (g - y * GR) * 4;
    if (x0 > HOUT - 4) x0 = HOUT - 4;
    float a0 = bias[co], a1 = a0, a2 = a0, a3 = a0;
    const float* base = in + (long)n * CIN * HIN * HIN;
    for (int ci = 0; ci < CIN; ++ci) {
        for (int ky = 0; ky < KS; ++ky) {
            const float* row = base + ((long)ci * HIN + y * STRIDE + ky) * HIN + x0 * STRIDE;
            float r[LEN];
            #pragma unroll
            for (int i = 0; i < LEN; ++i) r[i] = row[i];
            const float* wr = ws + (ci * KS + ky) * KS;
            #pragma unroll
            for (int kx = 0; kx < KS; ++kx) {
                const float wv = wr[kx];
                a0 = fmaf(wv, r[kx],              a0);
                a1 = fmaf(wv, r[kx + STRIDE],     a1);
                a2 = fmaf(wv, r[kx + 2 * STRIDE], a2);
                a3 = fmaf(wv, r[kx + 3 * STRIDE], a3);
            }
        }
    }
    __bf16* o = out + (((long)n * 16 + co) * HOUT + y) * HOUT + x0;
    o[0] = (__bf16)fmaxf(a0, 0.f); o[1] = (__bf16)fmaxf(a1, 0.f);
    o[2] = (__bf16)fmaxf(a2, 0.f); o[3] = (__bf16)fmaxf(a3, 0.f);
}

// ---------------- fc GEMM: C[64][N] += A[64][K] * W[N][K]^T, LDS-tiled, split-K ------
__global__ __launch_bounds__(256) void k_fc2(const float* __restrict__ A,
                                             const float* __restrict__ W,
                                             float* __restrict__ C,
                                             int N, int K, int kchunk)
{
    __shared__ float As[64][68];
    __shared__ float Bs[64][132];
    const int n0 = blockIdx.x * 128;
    const int kbeg = blockIdx.y * kchunk;
    const int tid = threadIdx.x;
    const int tm = tid >> 4, tn = tid & 15;
    const int am = tid >> 2, ac = tid & 3;
    const int bn = tid >> 1, bh = tid & 1;
    float acc[4][8] = {};
    for (int k0 = kbeg; k0 < kbeg + kchunk; k0 += 64) {
        #pragma unroll
        for (int q = 0; q < 4; ++q) {
            const int kk = ac * 16 + q * 4;
            const float4 v = *(const float4*)&A[(long)am * K + k0 + kk];
            As[kk + 0][am] = v.x; As[kk + 1][am] = v.y;
            As[kk + 2][am] = v.z; As[kk + 3][am] = v.w;
        }
        const int nn = n0 + bn;
        if (nn < N) {
            #pragma unroll
            for (int q = 0; q < 8; ++q) {
                const int kk = bh * 32 + q * 4;
                const float4 v = *(const float4*)&W[(long)nn * K + k0 + kk];
                Bs[kk + 0][bn] = v.x; Bs[kk + 1][bn] = v.y;
                Bs[kk + 2][bn] = v.z; Bs[kk + 3][bn] = v.w;
            }
        }
        __syncthreads();
        #pragma unroll 4
        for (int kk = 0; kk < 64; ++kk) {
            float a[4], b[8];
            #pragma unroll
            for (int i = 0; i < 4; ++i) a[i] = As[kk][tm * 4 + i];
            #pragma unroll
            for (int j = 0; j < 8; ++j) b[j] = Bs[kk][tn * 8 + j];
            #pragma unroll
            for (int i = 0; i < 4; ++i)
                #pragma unroll
                for (int j = 0; j < 8; ++j)
                    acc[i][j] = fmaf(a[i], b[j], acc[i][j]);
        }
        __syncthreads();
    }
    #pragma unroll
    for (int i = 0; i < 4; ++i) {
        const int m = tm * 4 + i;
        #pragma unroll
        for (int j = 0; j < 8; ++j) {
            const int nn = n0 + tn * 8 + j;
            if (nn < N) atomicAdd(&C[(long)m * N + nn], acc[i][j]);
        }
    }
}

__global__ __launch_bounds__(256) void k_bias_act(const float* __restrict__ C,
                                                  const float* __restrict__ bias,
                                                  float* __restrict__ out,
                                                  int N, int total, int relu)
{
    const int i = blockIdx.x * 256 + threadIdx.x;
    if (i >= total) return;
    float v = C[i] + bias[i % N];
    if (relu) v = fmaxf(v, 0.f);
    out[i] = v;
}

extern "C" void kernel_launch(void* const* d_in, const int* in_sizes, int n_in,
                              void* d_out, int out_size, void* d_ws, size_t ws_size,
                              hipStream_t stream)
{
    (void)in_sizes; (void)n_in; (void)out_size; (void)ws_size;
    const float* x       = (const float*)d_in[0];
    const float* conv1_w = (const float*)d_in[1];
    const float* conv1_b = (const float*)d_in[2];
    const float* rg_g    = (const float*)d_in[3];
    const float* rg_b    = (const float*)d_in[4];
    const float* rg_m    = (const float*)d_in[5];
    const float* rg_v    = (const float*)d_in[6];
    const float* rg_w    = (const float*)d_in[7];
    const float* rg_cb   = (const float*)d_in[8];
    const float* bn2_g   = (const float*)d_in[9];
    const float* bn2_b   = (const float*)d_in[10];
    const float* bn2_m   = (const float*)d_in[11];
    const float* bn2_v   = (const float*)d_in[12];
    const float* conv2_w = (const float*)d_in[13];
    const float* conv2_b = (const float*)d_in[14];
    const float* conv3_w = (const float*)d_in[15];
    const float* conv3_b = (const float*)d_in[16];
    const float* conv4_w = (const float*)d_in[17];
    const float* conv4_b = (const float*)d_in[18];
    const float* conv5_w = (const float*)d_in[19];
    const float* conv5_b = (const float*)d_in[20];
    const float* fc1_w   = (const float*)d_in[21];
    const float* fc1_b   = (const float*)d_in[22];
    const float* fc2_w   = (const float*)d_in[23];
    const float* fc2_b   = (const float*)d_in[24];
    const float* fc3_w   = (const float*)d_in[25];
    const float* fc3_b   = (const float*)d_in[26];

    float* ws = (float*)d_ws;
    __bf16* hp  = (__bf16*)ws;                       // pooled bn2 out bf16 (64,32,66,66) = 4,460,544 f
    float*  b2f = ws + 4460544;
    __bf16* wA2 = (__bf16*)(b2f);                    // 32768 bf16 = 16384 f
    __bf16* wA3 = (__bf16*)(b2f + 16384);            // 16384 bf16 = 8192 f
    __bf16* wA5 = (__bf16*)(b2f + 24576);            // 6656 bf16 -> 3328 f
    __bf16* h3  = (__bf16*)(b2f + 27904);            // conv2 out bf16 (64,16,59,59) = 1,782,272 f
    float*  h4  = b2f + 27904 + 1782272;             // conv3 out f32 (64,16,52,52) = 2,768,896 f
    __bf16* h5  = (__bf16*)(h4 + 2768896);           // conv4 out bf16 (64,16,24,24) = 294,912 f
    float*  h6  = (float*)h5 + 294912;               // conv5 out f32 == fc1 input (64,6400)
    float*  f1  = h6 + 409600;                       // fc1 out (64,4096)
    float*  f2  = f1 + 262144;                       // fc2 out (64,2048)
    float*  f3  = f2 + 131072;                       // fc3 tmp (64,12)

    k_fused<<<dim3(64, 8), 256, 0, stream>>>(x, conv1_w, conv1_b,
                                             rg_g, rg_b, rg_m, rg_v, rg_w, rg_cb,
                                             bn2_g, bn2_b, bn2_m, bn2_v, hp);

    k_wprep<<<dim3(128), 256, 0, stream>>>(conv2_w, wA2, 32, 8, 32);
    k_wprep<<<dim3(64), 256, 0, stream>>>(conv3_w, wA3, 16, 8, 32);
    k_wprep<<<dim3(26), 256, 0, stream>>>(conv5_w, wA5, 16, 5, 13);

    k_conv_mfma<__bf16, __bf16, 32, 8, 66, 59, 4><<<dim3(15, 64), 256, 0, stream>>>(hp, wA2, conv2_b, h3);
    k_conv_mfma<__bf16, float, 16, 8, 59, 52, 4><<<dim3(13, 64), 256, 0, stream>>>(h3, wA3, conv3_b, h4);
    k_conv<16, 6, 2, 52, 24><<<dim3(1, 16, 64), 256, 0, stream>>>(h4, conv4_w, conv4_b, h5);
    k_conv_mfma<__bf16, float, 16, 5, 24, 20, 10><<<dim3(2, 64), 256, 0, stream>>>(h5, wA5, conv5_b, h6);

    hipMemsetAsync(f1, 0, 262144 * sizeof(float), stream);
    k_fc2<<<dim3(32, 10), 256, 0, stream>>>(h6, fc1_w, f1, 4096, 6400, 640);
    k_bias_act<<<dim3((262144 + 255) / 256), 256, 0, stream>>>(f1, fc1_b, f1, 4096, 262144, 1);

    hipMemsetAsync(f2, 0, 131072 * sizeof(float), stream);
    k_fc2<<<dim3(16, 16), 256, 0, stream>>>(f1, fc2_w, f2, 2048, 4096, 256);
    k_bias_act<<<dim3((131072 + 255) / 256), 256, 0, stream>>>(f2, fc2_b, f2, 2048, 131072, 1);

    hipMemsetAsync(f3, 0, 768 * sizeof(float), stream);
    k_fc2<<<dim3(1, 16), 256, 0, stream>>>(f2, fc3_w, f3, 12, 2048, 128);
    k_bias_act<<<dim3(3), 256, 0, stream>>>(f3, fc3_b, (float*)d_out, 12, 768, 0);
}